// Round 3
// baseline (597.965 us; speedup 1.0000x reference)
//
#include <hip/hip_runtime.h>
#include <stdint.h>
#include <math.h>

// Match numpy's non-fused multiply-add rounding in distance/plane tests:
// a wrong argmin (or a boundary-mask flip) cascades into an O(1) output error.
// R1-R5 passed with absmax 0.0 using exactly these expression forms — keep them.
// p2 (precomputed in pack or recomputed in-scan/solo) uses the SAME expression
// form (contract off file-wide), so all paths are bit-identical.
#pragma clang fp contract(off)

#define BLOCK 1024
#define NW (BLOCK / 64)
#define PT 8                    // points per thread per full-scan step (slab-major)
#define PB 4                    // entries per thread per list-scan step (slab-major)
#define MAX_ITERS 50
#define SOLO_CAP 2048           // below this, wave 0 finishes alone (no barriers)
#define EPS_NORM 1e-8f
#define EPS_SEP (-1e-6f)

// R8 post-mortem (R2 bench): slab ROTATION regressed 481->597us, FETCH_SIZE
// 12.6->88MB — same-order lockstep streaming across the 32 blocks of an XCD is
// CONSTRUCTIVE L2 sharing (line fetched once, read 32x); rotation thrashed L2.
// Reverted. SoA planes (12B/pt full scans) kept; float4 pk kept for gathers.
// R8 new: occupancy 27% vs 50% instantaneous cap => ~half of all block-time is
// the single-wave solo tail (latency-bound scattered gathers). Solo now stages
// survivor coords into LDS once (16-wave cooperative fill at entry), then runs
// pure-LDS iterations with coords compacted in place alongside indices.
__global__ void pack_points(const float* __restrict__ pc,
                            float4* __restrict__ pk,
                            float* __restrict__ sx, float* __restrict__ sy,
                            float* __restrict__ sz, int N, int mode) {
    const int i = blockIdx.x * blockDim.x + threadIdx.x;
    if (i < N) {
        const float x = pc[3*i+0], y = pc[3*i+1], z = pc[3*i+2];
        float4 v; v.x = x; v.y = y; v.z = z;
        v.w = x*x + y*y + z*z;          // reference's exact p2 form
        pk[i] = v;
        if (mode >= 2) { sx[i] = x; sy[i] = y; sz[i] = z; }
    }
}

// One block per target. Survival state = LDS bitmask over N points (R3's
// proven representation; R5's plane-list retest was a serial divergent LDS
// chain and regressed 1.7x).
// Phase A: full-N scans, slab-major x8 (i = s*8192 + j*1024 + tid): coalesced
//          UNCONDITIONAL loads (R6: live-gating use, not load — conditional
//          loads killed MLP), 8 broadcast mask reads/thread, mask written via
//          8 ballots (lanes 0/32). When the incoming count fits 2*CAP the scan
//          also compacts survivors into an LDS list (shfl prefix-scan + 1
//          atomic/wave/step).
// Phase B: list-only scans (lane-stride-1 LDS reads: 2-way aliasing is free),
//          re-compacting in place (append positions provably stay below any
//          unread segment).
// Solo tail: below SOLO_CAP survivors, coords staged to LDS by all waves, then
// waves 1-15 retire; wave 0 runs remaining iterations wave-synchronously on
// LDS-resident data, zero __syncthreads, zero global gathers (except the
// 1/iter plane-point load).
// MODE: 0 = raw pc only; 1 = float4 pk; 2 = pk (gathers) + SoA (full scans).
template <int MODE>
__global__ __launch_bounds__(BLOCK) void convex_plane_kernel(
    const float* __restrict__ pc, const float4* __restrict__ pk,
    const float* __restrict__ sx, const float* __restrict__ sy,
    const float* __restrict__ sz, const float* __restrict__ tg,
    float* __restrict__ out, int N, int M, int CAP, int stepsA)
{
    extern __shared__ uint32_t smem[];
    const int tid  = threadIdx.x;
    const int lane = tid & 63;
    const int wv   = tid >> 6;
    const int m    = blockIdx.x;

    const int maskW = stepsA * (PT * BLOCK / 32);  // mask words
    uint32_t* mask  = smem;                        // [maskW]
    int*      list  = (int*)(smem + maskW);        // [CAP]
    float*    red_d = (float*)(list + CAP);        // [NW]
    int*      red_i = (int*)(red_d + NW);          // [NW]
    int*      cw    = red_i + NW;                  // [NW]
    int*      bcast = cw + NW;                     // [2] {argmin idx, count}
    int*      cnt   = bcast + 2;                   // [1] list-append cursor

    const float tx = tg[3*m+0], ty = tg[3*m+1], tz = tg[3*m+2];
    const float t2 = tx*tx + ty*ty + tz*tz;

    float* out_a = out;
    float* out_b = out + (size_t)MAX_ITERS * (size_t)M * 3;

    // gather fetch (phase B / solo entry / plane point): one dwordx4 if packed.
    auto ldp = [&](int ip, float& x, float& y, float& z, float& w) {
        if constexpr (MODE >= 1) {
            const float4 v = pk[ip];
            x = v.x; y = v.y; z = v.z; w = v.w;
        } else {
            const float* p = pc + 3 * (size_t)ip;
            x = p[0]; y = p[1]; z = p[2];
            w = x*x + y*y + z*z;
        }
    };

    // cross-wave finish: lexicographic (d2,idx) argmin + count sum; {idx,count}
    // returned to ALL threads via barrier-protected bcast (race-safe).
    auto finish = [&](float dmin, int imin, int mycnt, bool cntFromCursor) -> int2 {
        #pragma unroll
        for (int off = 32; off > 0; off >>= 1) {
            float od = __shfl_down(dmin, off, 64);
            int   oi = __shfl_down(imin, off, 64);
            int   oc = __shfl_down(mycnt, off, 64);
            if (od < dmin || (od == dmin && oi < imin)) { dmin = od; imin = oi; }
            mycnt += oc;
        }
        if (lane == 0) { red_d[wv] = dmin; red_i[wv] = imin; cw[wv] = mycnt; }
        __syncthreads();
        if (wv == 0) {
            float bd = (lane < NW) ? red_d[lane] : INFINITY;
            int   bi = (lane < NW) ? red_i[lane] : 0;
            int   c  = (lane < NW) ? cw[lane]    : 0;
            #pragma unroll
            for (int off = 8; off > 0; off >>= 1) {
                float od = __shfl_down(bd, off, 64);
                int   oi = __shfl_down(bi, off, 64);
                int   oc = __shfl_down(c,  off, 64);
                if (od < bd || (od == bd && oi < bi)) { bd = od; bi = oi; }
                c += oc;
            }
            if (lane == 0) { bcast[0] = bi; bcast[1] = cntFromCursor ? cnt[0] : c; }
        }
        __syncthreads();
        int2 r; r.x = bcast[0]; r.y = bcast[1];
        return r;
    };

    // Phase A: full-N scan, PT points/thread, slab-major (NO rotation — R8).
    // mode 0: all live, no plane test, no mask write (initial argmin)
    // mode 1: all live, test plane, write mask (k=0 cut; mask uninitialized)
    // mode 2: read mask, test plane, write mask
    auto scanA = [&](int mode, bool build,
                     float ax, float ay, float az, float b) -> int2 {
        if (tid == 0) cnt[0] = 0;
        __syncthreads();
        float dmin = INFINITY;
        int   imin = 0;
        int   mycnt = 0;
        for (int s = 0; s < stepsA; ++s) {
            const int ib    = s * PT * BLOCK + tid;
            const int wbase = s * (PT * BLOCK / 32);
            uint32_t live = 0;
            if (mode == 2) {
                #pragma unroll
                for (int j = 0; j < PT; ++j) {       // 8 independent broadcasts
                    uint32_t w = mask[wbase + j * (BLOCK / 32) + (tid >> 5)];
                    live |= ((w >> (tid & 31)) & 1u) << j;
                }
            } else {
                #pragma unroll
                for (int j = 0; j < PT; ++j)
                    if (ib + j * BLOCK < N) live |= (1u << j);
            }
            // UNCONDITIONAL clamped loads: all issued before any use (MLP).
            // Dead/tail lanes re-read point N-1; the live mask gates all uses.
            float px[PT], py[PT], pz[PT], pw[PT];
            if constexpr (MODE == 2) {
                #pragma unroll
                for (int j = 0; j < PT; ++j) {
                    int ip = ib + j * BLOCK;
                    ip = ip < N ? ip : N - 1;
                    px[j] = sx[ip]; py[j] = sy[ip]; pz[j] = sz[ip];
                }
                #pragma unroll
                for (int j = 0; j < PT; ++j)         // reference's exact p2 form
                    pw[j] = px[j]*px[j] + py[j]*py[j] + pz[j]*pz[j];
            } else {
                #pragma unroll
                for (int j = 0; j < PT; ++j) {
                    int ip = ib + j * BLOCK;
                    ip = ip < N ? ip : N - 1;
                    ldp(ip, px[j], py[j], pz[j], pw[j]);
                }
            }
            uint32_t keepm = 0;
            #pragma unroll
            for (int j = 0; j < PT; ++j) {
                if ((live >> j) & 1u) {
                    bool keep;
                    if (mode == 0) keep = true;
                    else {
                        float dt = ax*px[j] + ay*py[j] + az*pz[j] - b;
                        keep = (dt < EPS_SEP);       // !(dt >= EPS_SEP)
                    }
                    if (keep) {
                        keepm |= (1u << j);
                        float tp = tx*px[j] + ty*py[j] + tz*pz[j];
                        float d2 = t2 + pw[j] - 2.0f*tp;  // reference's exact form
                        const int i = ib + j * BLOCK;
                        // per-thread i ascends over (s,j); lexicographic ==
                        // first-index argmin either way
                        if (d2 < dmin || (d2 == dmin && i < imin)) {
                            dmin = d2; imin = i;
                        }
                    }
                }
            }
            if (mode != 0) {
                #pragma unroll
                for (int j = 0; j < PT; ++j) {       // mask write: 2 lanes/wave/j
                    unsigned long long bal = __ballot(((keepm >> j) & 1u) != 0u);
                    const int widx = wbase + j * (BLOCK / 32) + (wv << 1);
                    if (lane == 0)       mask[widx]     = (uint32_t)bal;
                    else if (lane == 32) mask[widx + 1] = (uint32_t)(bal >> 32);
                }
            }
            mycnt += (int)__popc(keepm);
            if (build) {                             // compact survivors
                int c = (int)__popc(keepm);
                int incl = c;
                #pragma unroll
                for (int off = 1; off < 64; off <<= 1) {
                    int o = __shfl_up(incl, off, 64);
                    if (lane >= off) incl += o;
                }
                const int excl = incl - c;
                const int tot  = __shfl(incl, 63, 64);
                int wb = 0;
                if (lane == 0) wb = atomicAdd(cnt, tot);
                wb = __shfl(wb, 0, 64);
                int pos = wb + excl;
                #pragma unroll
                for (int j = 0; j < PT; ++j) {
                    if ((keepm >> j) & 1u) {
                        if (pos < CAP) list[pos] = ib + j * BLOCK;
                        ++pos;
                    }
                }
            }
        }
        return finish(dmin, imin, mycnt, false);
    };

    // Phase B: list scan, slab-major, in-place re-compaction. Safe: per
    // segment, all reads complete (barrier) before appends, and append
    // positions stay strictly below any unread segment.
    auto scanB = [&](int count, float ax, float ay, float az, float b) -> int2 {
        if (tid == 0) cnt[0] = 0;
        __syncthreads();
        float dmin = INFINITY;
        int   imin = 0;
        const int per = BLOCK * PB;
        const int bsteps = (count + per - 1) / per;
        for (int s = 0; s < bsteps; ++s) {
            int jv[PB]; float d2v[PB];
            uint32_t keepm = 0;
            #pragma unroll
            for (int q = 0; q < PB; ++q) {
                const int e = s * per + q * BLOCK + tid;   // lane-stride 1
                if (e < count) {
                    const int j = list[e];
                    jv[q] = j;
                    float px, py, pz, p2;
                    ldp(j, px, py, pz, p2);
                    float dt = ax*px + ay*py + az*pz - b;
                    if (dt < EPS_SEP) {
                        keepm |= (1u << q);
                        float tp = tx*px + ty*py + tz*pz;
                        d2v[q] = t2 + p2 - 2.0f*tp;
                    }
                }
            }
            __syncthreads();                         // reads done before appends
            int c = (int)__popc(keepm);
            int incl = c;
            #pragma unroll
            for (int off = 1; off < 64; off <<= 1) {
                int o = __shfl_up(incl, off, 64);
                if (lane >= off) incl += o;
            }
            const int excl = incl - c;
            const int tot  = __shfl(incl, 63, 64);
            int wb = 0;
            if (lane == 0) wb = atomicAdd(cnt, tot);
            wb = __shfl(wb, 0, 64);
            int pos = wb + excl;
            #pragma unroll
            for (int q = 0; q < PB; ++q) {
                if ((keepm >> q) & 1u) {
                    list[pos] = jv[q];
                    // list order arbitrary -> lexicographic for exact ties
                    if (d2v[q] < dmin || (d2v[q] == dmin && jv[q] < imin)) {
                        dmin = d2v[q]; imin = jv[q];
                    }
                    ++pos;
                }
            }
        }
        __syncthreads();                             // all appends/atomics done
        return finish(dmin, imin, 0, true);          // count from cursor
    };

    bool comp = false;
    int2 rc = scanA(0, false, 0.f, 0.f, 0.f, 0.f);
    int idx = rc.x, count = rc.y;                    // count = N here

    for (int k = 0; k < MAX_ITERS; ++k) {
        // Solo tail: wave 0 finishes barrier-free on LDS-resident coords (R8).
        if (comp && count <= SOLO_CAP) {
            // Coord arrays live in the dead upper list region:
            // SOLO_CAP + 3*SOLO_CAP <= CAP for both CAP=32768 and CAP=8192.
            float* lx = (float*)(list + SOLO_CAP);
            float* ly = lx + SOLO_CAP;
            float* lz = ly + SOLO_CAP;
            // Cooperative 16-wave fill (one scattered gather, then LDS-only).
            for (int e = tid; e < count; e += BLOCK) {
                float x, y, z, w;
                ldp(list[e], x, y, z, w);
                lx[e] = x; ly[e] = y; lz[e] = z;
            }
            __syncthreads();                         // fill done, uniform sync
            if (wv != 0) return;                     // LDS persists while any wave lives
            for (; k < MAX_ITERS; ++k) {
                float cx, cy, cz, cw4;
                ldp(idx, cx, cy, cz, cw4);
                const float vx = cx - tx, vy = cy - ty, vz = cz - tz;
                const float nrm = sqrtf(vx*vx + vy*vy + vz*vz);
                const float den = nrm + EPS_NORM;
                const float ax = vx / den, ay = vy / den, az = vz / den;
                const float b  = ax*cx + ay*cy + az*cz;
                if (count == 0) {                    // constant tail: bulk write
                    for (int q = lane; q < MAX_ITERS - k; q += 64) {
                        const int kk = k + q;
                        const size_t oa = ((size_t)kk * M + m) * 3;
                        out_a[oa+0] = ax; out_a[oa+1] = ay; out_a[oa+2] = az;
                        out_b[(size_t)kk * M + m] = b;
                    }
                    return;
                }
                if (lane == 0) {
                    const size_t oa = ((size_t)k * M + m) * 3;
                    out_a[oa+0] = ax; out_a[oa+1] = ay; out_a[oa+2] = az;
                    out_b[(size_t)k * M + m] = b;
                }
                if (k + 1 < MAX_ITERS) {
                    float dmin = INFINITY; int imin = 0; int wcur = 0;
                    for (int e0 = 0; e0 < count; e0 += 64) {
                        const int e = e0 + lane;
                        bool keep = false; int j = 0;
                        float d2v = 0.f, px = 0.f, py = 0.f, pz = 0.f;
                        if (e < count) {
                            j = list[e];
                            px = lx[e]; py = ly[e]; pz = lz[e];
                            float dt = ax*px + ay*py + az*pz - b;
                            if (dt < EPS_SEP) {
                                keep = true;
                                // identical bits to pack's w (same expr form)
                                float p2 = px*px + py*py + pz*pz;
                                float tp = tx*px + ty*py + tz*pz;
                                d2v = t2 + p2 - 2.0f*tp;
                            }
                        }
                        // in-place compact: pos < wcur+64 <= e0+64, and chunk
                        // [e0,e0+64) is already in registers (reads precede
                        // writes in wave-synchronous program order).
                        unsigned long long bal = __ballot(keep);
                        int pos = wcur + (int)__popcll(bal & ((1ull << lane) - 1ull));
                        if (keep) {
                            list[pos] = j;
                            lx[pos] = px; ly[pos] = py; lz[pos] = pz;
                            if (d2v < dmin || (d2v == dmin && j < imin)) {
                                dmin = d2v; imin = j;
                            }
                        }
                        wcur += (int)__popcll(bal);
                    }
                    #pragma unroll
                    for (int off = 32; off > 0; off >>= 1) {
                        float od = __shfl_down(dmin, off, 64);
                        int   oi = __shfl_down(imin, off, 64);
                        if (od < dmin || (od == dmin && oi < imin)) { dmin = od; imin = oi; }
                    }
                    idx = __shfl(imin, 0, 64);
                    count = wcur;                    // uniform across lanes
                }
            }
            return;
        }

        float cx, cy, cz, cw4;
        ldp(idx, cx, cy, cz, cw4);
        const float vx = cx - tx, vy = cy - ty, vz = cz - tz;
        const float nrm = sqrtf(vx*vx + vy*vy + vz*vz);
        const float den = nrm + EPS_NORM;
        const float ax = vx / den, ay = vy / den, az = vz / den;
        const float b  = ax*cx + ay*cy + az*cz;      // b = sum(a * closest)

        if (count == 0) {                            // constant tail: bulk write
            for (int q = tid; q < MAX_ITERS - k; q += BLOCK) {
                const int kk = k + q;
                const size_t oa = ((size_t)kk * M + m) * 3;
                out_a[oa+0] = ax; out_a[oa+1] = ay; out_a[oa+2] = az;
                out_b[(size_t)kk * M + m] = b;
            }
            return;
        }
        if (tid == 0) {
            const size_t oa = ((size_t)k * M + m) * 3;
            out_a[oa+0] = ax; out_a[oa+1] = ay; out_a[oa+2] = az;
            out_b[(size_t)k * M + m] = b;
        }
        if (k + 1 < MAX_ITERS) {                     // last update unobservable
            if (comp) {
                rc = scanB(count, ax, ay, az, b);
            } else {
                const bool build = (count <= 2 * CAP);
                rc = scanA(k == 0 ? 1 : 2, build, ax, ay, az, b);
                if (build && rc.y <= CAP) comp = true;
            }
            idx = rc.x; count = rc.y;
        }
    }
}

extern "C" void kernel_launch(void* const* d_in, const int* in_sizes, int n_in,
                              void* d_out, int out_size, void* d_ws, size_t ws_size,
                              hipStream_t stream) {
    const float* pc = (const float*)d_in[0];
    const float* tg = (const float*)d_in[1];
    float* out = (float*)d_out;
    const int N = in_sizes[0] / 3;
    const int M = in_sizes[1] / 3;
    const int stepsA = (N + BLOCK * PT - 1) / (BLOCK * PT);
    const size_t maskB  = (size_t)stepsA * (PT * BLOCK / 32) * sizeof(uint32_t);
    const size_t fixedB = NW * (2 * sizeof(int) + sizeof(float)) + 3 * sizeof(int);
    const size_t need16 = (size_t)N * sizeof(float4);          // pk only
    const size_t need28 = need16 + 3 * (size_t)N * sizeof(float); // + SoA

    int wsmode = 0;
    if (d_ws && ws_size >= need28) wsmode = 2;
    else if (d_ws && ws_size >= need16) wsmode = 1;

    float4* pk = (float4*)d_ws;
    float*  sxp = (float*)((char*)d_ws + need16);
    float*  syp = sxp + N;
    float*  szp = syp + N;

    int CAP = 32768;                                 // 128 KB list; total ~157 KB LDS
    size_t smem = maskB + (size_t)CAP * sizeof(int) + fixedB;
    const void* fn = (wsmode == 2) ? (const void*)convex_plane_kernel<2>
                   : (wsmode == 1) ? (const void*)convex_plane_kernel<1>
                                   : (const void*)convex_plane_kernel<0>;
    if (hipFuncSetAttribute(fn, hipFuncAttributeMaxDynamicSharedMemorySize,
                            (int)smem) != hipSuccess) {
        CAP = 8192;                                  // stay within default 64 KB
        smem = maskB + (size_t)CAP * sizeof(int) + fixedB;
    }
    if (wsmode >= 1) {
        pack_points<<<(N + 255) / 256, 256, 0, stream>>>(pc, pk, sxp, syp, szp,
                                                         N, wsmode);
    }
    if (wsmode == 2) {
        convex_plane_kernel<2><<<M, BLOCK, smem, stream>>>(
            pc, pk, sxp, syp, szp, tg, out, N, M, CAP, stepsA);
    } else if (wsmode == 1) {
        convex_plane_kernel<1><<<M, BLOCK, smem, stream>>>(
            pc, pk, nullptr, nullptr, nullptr, tg, out, N, M, CAP, stepsA);
    } else {
        convex_plane_kernel<0><<<M, BLOCK, smem, stream>>>(
            pc, nullptr, nullptr, nullptr, nullptr, tg, out, N, M, CAP, stepsA);
    }
}

// Round 4
// 551.349 us; speedup vs baseline: 1.0845x; 1.0845x over previous
//
#include <hip/hip_runtime.h>
#include <stdint.h>
#include <math.h>

// Match numpy's non-fused multiply-add rounding in distance/plane tests:
// a wrong argmin (or a boundary-mask flip) cascades into an O(1) output error.
// All d2 / plane expressions keep exactly these forms (contract off file-wide);
// p2 recomputed anywhere uses x*x+y*y+z*z — bit-identical across paths.
#pragma clang fp contract(off)

#define BLOCK 1024
#define NW (BLOCK / 64)
#define PT 8                    // points per thread per full-scan step (slab-major)
#define PB 4                    // entries per thread per list-scan step (slab-major)
#define MAX_ITERS 50
#define SOLO_CAP 2048           // below this, wave 0 finishes alone (no barriers)
#define EPS_NORM 1e-8f
#define EPS_SEP (-1e-6f)

// R9 post-mortem: SoA planes (R2/R3) pushed the scan working set to 5.6MB >
// 4MiB per-XCD L2 -> every full pass refetched from L3 (FETCH 78-88MB, model:
// 8 XCD x 4 pass x 2.4MB = 77MB == measured). Reverted to float4-only scans
// (3.2MB, L2-resident, FETCH ~12MB in R1). Occupancy 27% vs 50% inst. =
// mean block lifetime ~54% of max: ~2x straggler imbalance. Stragglers decay
// slowly (survival Phi(a.t) up to ~0.84/iter) -> 7-9 full-N passes before the
// LDS list engages. R9 fix: per-block GLOBAL coord list {x,y,z,idx} in ws
// (CAPG up to 131072), built during a masked pass once incoming <= 2*CAPG;
// all later passes are CONTIGUOUS float4 list scans with in-place compaction
// (read-frontier proof as scanB; single CU => L1-coherent). Stragglers' extra
// passes become <=1MB streams instead of 3.2MB full-N scans.
__global__ void pack_points(const float* __restrict__ pc,
                            float4* __restrict__ pk, int N) {
    const int i = blockIdx.x * blockDim.x + threadIdx.x;
    if (i < N) {
        const float x = pc[3*i+0], y = pc[3*i+1], z = pc[3*i+2];
        float4 v; v.x = x; v.y = y; v.z = z;
        v.w = x*x + y*y + z*z;          // reference's exact p2 form
        pk[i] = v;
    }
}

// One block per target. Survival state tiers:
//   full-N bitmask (LDS)  ->  global coord list (ws, contiguous)  ->
//   LDS index list (fallback when ws small)  ->  LDS solo tail (wave 0).
// MODE: 0 = raw pc only; 1 = float4 pk (R1 behavior); 3 = pk + global list.
template <int MODE>
__global__ __launch_bounds__(BLOCK) void convex_plane_kernel(
    const float* __restrict__ pc, const float4* __restrict__ pk,
    float4* __restrict__ glist, const float* __restrict__ tg,
    float* __restrict__ out, int N, int M, int CAP, int CAPG, int stepsA)
{
    extern __shared__ uint32_t smem[];
    const int tid  = threadIdx.x;
    const int lane = tid & 63;
    const int wv   = tid >> 6;
    const int m    = blockIdx.x;

    const int maskW = stepsA * (PT * BLOCK / 32);  // mask words
    uint32_t* mask  = smem;                        // [maskW]
    int*      list  = (int*)(smem + maskW);        // [CAP]
    float*    red_d = (float*)(list + CAP);        // [NW]
    int*      red_i = (int*)(red_d + NW);          // [NW]
    int*      cw    = red_i + NW;                  // [NW]
    int*      bcast = cw + NW;                     // [2] {argmin idx, count}
    int*      cnt   = bcast + 2;                   // [1] list-append cursor

    float4* gl = (MODE == 3) ? glist + (size_t)m * (size_t)CAPG : nullptr;

    const float tx = tg[3*m+0], ty = tg[3*m+1], tz = tg[3*m+2];
    const float t2 = tx*tx + ty*ty + tz*tz;

    float* out_a = out;
    float* out_b = out + (size_t)MAX_ITERS * (size_t)M * 3;

    // gather fetch (plane point / LDS-list path / solo fill): one dwordx4.
    auto ldp = [&](int ip, float& x, float& y, float& z, float& w) {
        if constexpr (MODE >= 1) {
            const float4 v = pk[ip];
            x = v.x; y = v.y; z = v.z; w = v.w;
        } else {
            const float* p = pc + 3 * (size_t)ip;
            x = p[0]; y = p[1]; z = p[2];
            w = x*x + y*y + z*z;
        }
    };

    // cross-wave finish: lexicographic (d2,idx) argmin + count sum; {idx,count}
    // returned to ALL threads via barrier-protected bcast (race-safe).
    auto finish = [&](float dmin, int imin, int mycnt, bool cntFromCursor) -> int2 {
        #pragma unroll
        for (int off = 32; off > 0; off >>= 1) {
            float od = __shfl_down(dmin, off, 64);
            int   oi = __shfl_down(imin, off, 64);
            int   oc = __shfl_down(mycnt, off, 64);
            if (od < dmin || (od == dmin && oi < imin)) { dmin = od; imin = oi; }
            mycnt += oc;
        }
        if (lane == 0) { red_d[wv] = dmin; red_i[wv] = imin; cw[wv] = mycnt; }
        __syncthreads();
        if (wv == 0) {
            float bd = (lane < NW) ? red_d[lane] : INFINITY;
            int   bi = (lane < NW) ? red_i[lane] : 0;
            int   c  = (lane < NW) ? cw[lane]    : 0;
            #pragma unroll
            for (int off = 8; off > 0; off >>= 1) {
                float od = __shfl_down(bd, off, 64);
                int   oi = __shfl_down(bi, off, 64);
                int   oc = __shfl_down(c,  off, 64);
                if (od < bd || (od == bd && oi < bi)) { bd = od; bi = oi; }
                c += oc;
            }
            if (lane == 0) { bcast[0] = bi; bcast[1] = cntFromCursor ? cnt[0] : c; }
        }
        __syncthreads();
        int2 r; r.x = bcast[0]; r.y = bcast[1];
        return r;
    };

    // Phase A: full-N scan, PT points/thread, slab-major (no rotation — R8:
    // lockstep streaming is constructive L2 sharing).
    // mode 0: all live, no plane test, no mask write (initial argmin)
    // mode 1: all live, test plane, write mask (k=0 cut; mask uninitialized)
    // mode 2: read mask, test plane, write mask
    // buildL: compact survivor indices into LDS list (cap CAP).
    // buildG: compact survivor coords {x,y,z,idx} into global list (cap CAPG).
    auto scanA = [&](int mode, bool buildL, bool buildG,
                     float ax, float ay, float az, float b) -> int2 {
        if (tid == 0) cnt[0] = 0;
        __syncthreads();
        float dmin = INFINITY;
        int   imin = 0;
        int   mycnt = 0;
        for (int s = 0; s < stepsA; ++s) {
            const int ib    = s * PT * BLOCK + tid;
            const int wbase = s * (PT * BLOCK / 32);
            uint32_t live = 0;
            if (mode == 2) {
                #pragma unroll
                for (int j = 0; j < PT; ++j) {       // 8 independent broadcasts
                    uint32_t w = mask[wbase + j * (BLOCK / 32) + (tid >> 5)];
                    live |= ((w >> (tid & 31)) & 1u) << j;
                }
            } else {
                #pragma unroll
                for (int j = 0; j < PT; ++j)
                    if (ib + j * BLOCK < N) live |= (1u << j);
            }
            // UNCONDITIONAL clamped loads: all issued before any use (MLP).
            // Dead/tail lanes re-read point N-1; the live mask gates all uses.
            float px[PT], py[PT], pz[PT], pw[PT];
            #pragma unroll
            for (int j = 0; j < PT; ++j) {
                int ip = ib + j * BLOCK;
                ip = ip < N ? ip : N - 1;
                ldp(ip, px[j], py[j], pz[j], pw[j]);
            }
            uint32_t keepm = 0;
            #pragma unroll
            for (int j = 0; j < PT; ++j) {
                if ((live >> j) & 1u) {
                    bool keep;
                    if (mode == 0) keep = true;
                    else {
                        float dt = ax*px[j] + ay*py[j] + az*pz[j] - b;
                        keep = (dt < EPS_SEP);       // !(dt >= EPS_SEP)
                    }
                    if (keep) {
                        keepm |= (1u << j);
                        float tp = tx*px[j] + ty*py[j] + tz*pz[j];
                        float d2 = t2 + pw[j] - 2.0f*tp;  // reference's exact form
                        const int i = ib + j * BLOCK;
                        if (d2 < dmin || (d2 == dmin && i < imin)) {
                            dmin = d2; imin = i;
                        }
                    }
                }
            }
            if (mode != 0) {
                #pragma unroll
                for (int j = 0; j < PT; ++j) {       // mask write: 2 lanes/wave/j
                    unsigned long long bal = __ballot(((keepm >> j) & 1u) != 0u);
                    const int widx = wbase + j * (BLOCK / 32) + (wv << 1);
                    if (lane == 0)       mask[widx]     = (uint32_t)bal;
                    else if (lane == 32) mask[widx + 1] = (uint32_t)(bal >> 32);
                }
            }
            mycnt += (int)__popc(keepm);
            if (buildL || buildG) {                  // compact survivors
                int c = (int)__popc(keepm);
                int incl = c;
                #pragma unroll
                for (int off = 1; off < 64; off <<= 1) {
                    int o = __shfl_up(incl, off, 64);
                    if (lane >= off) incl += o;
                }
                const int excl = incl - c;
                const int tot  = __shfl(incl, 63, 64);
                int wb = 0;
                if (lane == 0) wb = atomicAdd(cnt, tot);
                wb = __shfl(wb, 0, 64);
                int pos = wb + excl;
                #pragma unroll
                for (int j = 0; j < PT; ++j) {
                    if ((keepm >> j) & 1u) {
                        const int i = ib + j * BLOCK;
                        if (buildL && pos < CAP) list[pos] = i;
                        if constexpr (MODE == 3) {
                            if (buildG && pos < CAPG) {
                                float4 v; v.x = px[j]; v.y = py[j];
                                v.z = pz[j]; v.w = __int_as_float(i);
                                gl[pos] = v;
                            }
                        }
                        ++pos;
                    }
                }
            }
        }
        return finish(dmin, imin, mycnt, false);
    };

    // Phase G (MODE 3): contiguous global coord-list scan, in-place
    // re-compaction. Safety: per segment all reads complete (barrier) before
    // appends; append positions provably stay below any unread segment
    // (cursor after segment s <= (s+1)*per). Single CU => L1-coherent across
    // passes; __syncthreads drains vmcnt before the barrier.
    auto scanG = [&](int count, float ax, float ay, float az, float b) -> int2 {
        if (tid == 0) cnt[0] = 0;
        __syncthreads();
        float dmin = INFINITY;
        int   imin = 0;
        const int per = BLOCK * PB;
        const int bsteps = (count + per - 1) / per;
        for (int s = 0; s < bsteps; ++s) {
            float4 v[PB]; float d2v[PB]; int iv[PB];
            uint32_t keepm = 0;
            #pragma unroll
            for (int q = 0; q < PB; ++q) {           // unconditional clamped
                int e = s * per + q * BLOCK + tid;   // lane-stride 1, coalesced
                e = e < count ? e : count - 1;
                v[q] = gl[e];
            }
            #pragma unroll
            for (int q = 0; q < PB; ++q) {
                const int e = s * per + q * BLOCK + tid;
                if (e < count) {
                    const float x = v[q].x, y = v[q].y, z = v[q].z;
                    iv[q] = __float_as_int(v[q].w);
                    float dt = ax*x + ay*y + az*z - b;
                    if (dt < EPS_SEP) {
                        keepm |= (1u << q);
                        float p2 = x*x + y*y + z*z;  // exact reference form
                        float tp = tx*x + ty*y + tz*z;
                        d2v[q] = t2 + p2 - 2.0f*tp;
                    }
                }
            }
            __syncthreads();                         // reads done before appends
            int c = (int)__popc(keepm);
            int incl = c;
            #pragma unroll
            for (int off = 1; off < 64; off <<= 1) {
                int o = __shfl_up(incl, off, 64);
                if (lane >= off) incl += o;
            }
            const int excl = incl - c;
            const int tot  = __shfl(incl, 63, 64);
            int wb = 0;
            if (lane == 0) wb = atomicAdd(cnt, tot);
            wb = __shfl(wb, 0, 64);
            int pos = wb + excl;
            #pragma unroll
            for (int q = 0; q < PB; ++q) {
                if ((keepm >> q) & 1u) {
                    gl[pos] = v[q];
                    if (d2v[q] < dmin || (d2v[q] == dmin && iv[q] < imin)) {
                        dmin = d2v[q]; imin = iv[q];
                    }
                    ++pos;
                }
            }
        }
        __syncthreads();                             // all appends/atomics done
        return finish(dmin, imin, 0, true);          // count from cursor
    };

    // Phase B (fallback when ws too small): LDS index-list scan, in-place.
    auto scanB = [&](int count, float ax, float ay, float az, float b) -> int2 {
        if (tid == 0) cnt[0] = 0;
        __syncthreads();
        float dmin = INFINITY;
        int   imin = 0;
        const int per = BLOCK * PB;
        const int bsteps = (count + per - 1) / per;
        for (int s = 0; s < bsteps; ++s) {
            int jv[PB]; float d2v[PB];
            uint32_t keepm = 0;
            #pragma unroll
            for (int q = 0; q < PB; ++q) {
                const int e = s * per + q * BLOCK + tid;   // lane-stride 1
                if (e < count) {
                    const int j = list[e];
                    jv[q] = j;
                    float px, py, pz, p2;
                    ldp(j, px, py, pz, p2);
                    float dt = ax*px + ay*py + az*pz - b;
                    if (dt < EPS_SEP) {
                        keepm |= (1u << q);
                        float tp = tx*px + ty*py + tz*pz;
                        d2v[q] = t2 + p2 - 2.0f*tp;
                    }
                }
            }
            __syncthreads();                         // reads done before appends
            int c = (int)__popc(keepm);
            int incl = c;
            #pragma unroll
            for (int off = 1; off < 64; off <<= 1) {
                int o = __shfl_up(incl, off, 64);
                if (lane >= off) incl += o;
            }
            const int excl = incl - c;
            const int tot  = __shfl(incl, 63, 64);
            int wb = 0;
            if (lane == 0) wb = atomicAdd(cnt, tot);
            wb = __shfl(wb, 0, 64);
            int pos = wb + excl;
            #pragma unroll
            for (int q = 0; q < PB; ++q) {
                if ((keepm >> q) & 1u) {
                    list[pos] = jv[q];
                    if (d2v[q] < dmin || (d2v[q] == dmin && jv[q] < imin)) {
                        dmin = d2v[q]; imin = jv[q];
                    }
                    ++pos;
                }
            }
        }
        __syncthreads();                             // all appends/atomics done
        return finish(dmin, imin, 0, true);          // count from cursor
    };

    bool comp = false, compG = false;
    int2 rc = scanA(0, false, false, 0.f, 0.f, 0.f, 0.f);
    int idx = rc.x, count = rc.y;                    // count = N here

    for (int k = 0; k < MAX_ITERS; ++k) {
        // Solo tail: wave 0 finishes barrier-free on LDS-resident coords.
        if ((comp || compG) && count <= SOLO_CAP) {
            // Coord arrays in the dead upper list region:
            // SOLO_CAP + 3*SOLO_CAP <= CAP for CAP=32768 and CAP=8192.
            float* lx = (float*)(list + SOLO_CAP);
            float* ly = lx + SOLO_CAP;
            float* lz = ly + SOLO_CAP;
            if (compG) {
                if constexpr (MODE == 3) {
                    for (int e = tid; e < count; e += BLOCK) {  // contiguous
                        const float4 v = gl[e];
                        lx[e] = v.x; ly[e] = v.y; lz[e] = v.z;
                        list[e] = __float_as_int(v.w);
                    }
                }
            } else {
                for (int e = tid; e < count; e += BLOCK) {      // gather
                    float x, y, z, w;
                    ldp(list[e], x, y, z, w);
                    lx[e] = x; ly[e] = y; lz[e] = z;
                }
            }
            __syncthreads();                         // fill done, uniform sync
            if (wv != 0) return;                     // LDS persists while any wave lives
            for (; k < MAX_ITERS; ++k) {
                float cx, cy, cz, cw4;
                ldp(idx, cx, cy, cz, cw4);
                const float vx = cx - tx, vy = cy - ty, vz = cz - tz;
                const float nrm = sqrtf(vx*vx + vy*vy + vz*vz);
                const float den = nrm + EPS_NORM;
                const float ax = vx / den, ay = vy / den, az = vz / den;
                const float b  = ax*cx + ay*cy + az*cz;
                if (count == 0) {                    // constant tail: bulk write
                    for (int q = lane; q < MAX_ITERS - k; q += 64) {
                        const int kk = k + q;
                        const size_t oa = ((size_t)kk * M + m) * 3;
                        out_a[oa+0] = ax; out_a[oa+1] = ay; out_a[oa+2] = az;
                        out_b[(size_t)kk * M + m] = b;
                    }
                    return;
                }
                if (lane == 0) {
                    const size_t oa = ((size_t)k * M + m) * 3;
                    out_a[oa+0] = ax; out_a[oa+1] = ay; out_a[oa+2] = az;
                    out_b[(size_t)k * M + m] = b;
                }
                if (k + 1 < MAX_ITERS) {
                    float dmin = INFINITY; int imin = 0; int wcur = 0;
                    for (int e0 = 0; e0 < count; e0 += 64) {
                        const int e = e0 + lane;
                        bool keep = false; int j = 0;
                        float d2v = 0.f, px = 0.f, py = 0.f, pz = 0.f;
                        if (e < count) {
                            j = list[e];
                            px = lx[e]; py = ly[e]; pz = lz[e];
                            float dt = ax*px + ay*py + az*pz - b;
                            if (dt < EPS_SEP) {
                                keep = true;
                                float p2 = px*px + py*py + pz*pz;
                                float tp = tx*px + ty*py + tz*pz;
                                d2v = t2 + p2 - 2.0f*tp;
                            }
                        }
                        // in-place compact: pos < wcur+64 <= e0+64; chunk
                        // [e0,e0+64) already in registers.
                        unsigned long long bal = __ballot(keep);
                        int pos = wcur + (int)__popcll(bal & ((1ull << lane) - 1ull));
                        if (keep) {
                            list[pos] = j;
                            lx[pos] = px; ly[pos] = py; lz[pos] = pz;
                            if (d2v < dmin || (d2v == dmin && j < imin)) {
                                dmin = d2v; imin = j;
                            }
                        }
                        wcur += (int)__popcll(bal);
                    }
                    #pragma unroll
                    for (int off = 32; off > 0; off >>= 1) {
                        float od = __shfl_down(dmin, off, 64);
                        int   oi = __shfl_down(imin, off, 64);
                        if (od < dmin || (od == dmin && oi < imin)) { dmin = od; imin = oi; }
                    }
                    idx = __shfl(imin, 0, 64);
                    count = wcur;                    // uniform across lanes
                }
            }
            return;
        }

        float cx, cy, cz, cw4;
        ldp(idx, cx, cy, cz, cw4);
        const float vx = cx - tx, vy = cy - ty, vz = cz - tz;
        const float nrm = sqrtf(vx*vx + vy*vy + vz*vz);
        const float den = nrm + EPS_NORM;
        const float ax = vx / den, ay = vy / den, az = vz / den;
        const float b  = ax*cx + ay*cy + az*cz;      // b = sum(a * closest)

        if (count == 0) {                            // constant tail: bulk write
            for (int q = tid; q < MAX_ITERS - k; q += BLOCK) {
                const int kk = k + q;
                const size_t oa = ((size_t)kk * M + m) * 3;
                out_a[oa+0] = ax; out_a[oa+1] = ay; out_a[oa+2] = az;
                out_b[(size_t)kk * M + m] = b;
            }
            return;
        }
        if (tid == 0) {
            const size_t oa = ((size_t)k * M + m) * 3;
            out_a[oa+0] = ax; out_a[oa+1] = ay; out_a[oa+2] = az;
            out_b[(size_t)k * M + m] = b;
        }
        if (k + 1 < MAX_ITERS) {                     // last update unobservable
            if (compG) {
                rc = scanG(count, ax, ay, az, b);
            } else if (comp) {
                rc = scanB(count, ax, ay, az, b);
            } else {
                const bool bG = (MODE == 3) && CAPG > 0 && count <= 2 * CAPG;
                const bool bL = count <= 2 * CAP;
                rc = scanA(k == 0 ? 1 : 2, bL, bG, ax, ay, az, b);
                if (bG && rc.y <= CAPG) compG = true;       // prefer global list
                else if (bL && rc.y <= CAP) comp = true;
            }
            idx = rc.x; count = rc.y;
        }
    }
}

extern "C" void kernel_launch(void* const* d_in, const int* in_sizes, int n_in,
                              void* d_out, int out_size, void* d_ws, size_t ws_size,
                              hipStream_t stream) {
    const float* pc = (const float*)d_in[0];
    const float* tg = (const float*)d_in[1];
    float* out = (float*)d_out;
    const int N = in_sizes[0] / 3;
    const int M = in_sizes[1] / 3;
    const int stepsA = (N + BLOCK * PT - 1) / (BLOCK * PT);
    const size_t maskB  = (size_t)stepsA * (PT * BLOCK / 32) * sizeof(uint32_t);
    const size_t fixedB = NW * (2 * sizeof(int) + sizeof(float)) + 3 * sizeof(int);
    const size_t pkB    = (size_t)N * sizeof(float4);

    // ws layout: [pk: N float4][glist: M * CAPG float4] — CAPG adaptive.
    int wsmode = 0;
    int CAPG = 0;
    if (d_ws && ws_size >= pkB) {
        wsmode = 1;
        const size_t rem = ws_size - pkB;
        size_t cg = rem / ((size_t)M * sizeof(float4));
        if (cg > 131072) cg = 131072;
        if (cg >= 8192) { CAPG = (int)cg; wsmode = 3; }
    }
    float4* pk = (float4*)d_ws;
    float4* glp = (float4*)((char*)d_ws + pkB);

    int CAP = 32768;                                 // 128 KB list; total ~157 KB LDS
    size_t smem = maskB + (size_t)CAP * sizeof(int) + fixedB;
    const void* fn = (wsmode == 3) ? (const void*)convex_plane_kernel<3>
                   : (wsmode == 1) ? (const void*)convex_plane_kernel<1>
                                   : (const void*)convex_plane_kernel<0>;
    if (hipFuncSetAttribute(fn, hipFuncAttributeMaxDynamicSharedMemorySize,
                            (int)smem) != hipSuccess) {
        CAP = 8192;                                  // stay within default 64 KB
        smem = maskB + (size_t)CAP * sizeof(int) + fixedB;
    }
    if (wsmode >= 1) {
        pack_points<<<(N + 255) / 256, 256, 0, stream>>>(pc, pk, N);
    }
    if (wsmode == 3) {
        convex_plane_kernel<3><<<M, BLOCK, smem, stream>>>(
            pc, pk, glp, tg, out, N, M, CAP, CAPG, stepsA);
    } else if (wsmode == 1) {
        convex_plane_kernel<1><<<M, BLOCK, smem, stream>>>(
            pc, pk, nullptr, tg, out, N, M, CAP, 0, stepsA);
    } else {
        convex_plane_kernel<0><<<M, BLOCK, smem, stream>>>(
            pc, nullptr, nullptr, tg, out, N, M, CAP, 0, stepsA);
    }
}

// Round 5
// 547.541 us; speedup vs baseline: 1.0921x; 1.0070x over previous
//
#include <hip/hip_runtime.h>
#include <stdint.h>
#include <math.h>

// Match numpy's non-fused multiply-add rounding in distance/plane tests:
// a wrong argmin (or a boundary-mask flip) cascades into an O(1) output error.
// All d2 / plane expressions keep exactly these forms (contract off file-wide);
// p2 everywhere is x*x+y*y+z*z — bit-identical to the reference's sum(p*p).
#pragma clang fp contract(off)

#define BLOCK 1024
#define NW (BLOCK / 64)
#define PT 8                    // points per thread per full-scan step (slab-major)
#define PB 4                    // entries per thread per list-scan step (slab-major)
#define MAX_ITERS 50
#define SOLO_CAP 2048           // below this, wave 0 finishes alone (no barriers)
#define EPS_NORM 1e-8f
#define EPS_SEP (-1e-6f)

// R10 memory-hierarchy law (from R3/R4 counter post-mortems):
//   - Per-block survivor state MUST be LDS-resident (<=128KB). Global per-block
//     lists (R4) = 32 blocks/XCD x ~2MB >> 4MiB L2 -> FETCH 114MB WRITE 146MB,
//     551us. LDS list (R1) = 481us.
//   - Shared read-only points must be ONE array small enough that all phases of
//     all 32 blocks/XCD share the same L2 lines. Two arrays (R3: SoA scans +
//     pk gathers, 5.6MB mixed) -> 78MB refetch/pass, 597us.
// R10 change: single shared array = raw pc (12B/pt, 2.4MB). Full passes are
// L2-BW-bound (VALU model 10us vs L2 24us per pass == measured VALUBusy ~42%),
// so -25% bytes/pt is a direct cut on the dominant phase. Loads stay
// UNCONDITIONAL+clamped (R6: conditional loads serialized; R0's 12B path was
// never retried with unconditional loads). p2 recomputed under keep (exact
// reference form). Earlier list-build attempts (incoming <= 2.5*CAP; failed
// build costs only a prefix scan).
//
// One block per target. Survival state = LDS bitmask over N points; tiers:
//   full-N bitmask scans -> LDS index list -> LDS coord solo tail (wave 0).
__global__ __launch_bounds__(BLOCK) void convex_plane_kernel(
    const float* __restrict__ pc, const float* __restrict__ tg,
    float* __restrict__ out, int N, int M, int CAP, int stepsA)
{
    extern __shared__ uint32_t smem[];
    const int tid  = threadIdx.x;
    const int lane = tid & 63;
    const int wv   = tid >> 6;
    const int m    = blockIdx.x;

    const int maskW = stepsA * (PT * BLOCK / 32);  // mask words
    uint32_t* mask  = smem;                        // [maskW]
    int*      list  = (int*)(smem + maskW);        // [CAP]
    float*    red_d = (float*)(list + CAP);        // [NW]
    int*      red_i = (int*)(red_d + NW);          // [NW]
    int*      cw    = red_i + NW;                  // [NW]
    int*      bcast = cw + NW;                     // [2] {argmin idx, count}
    int*      cnt   = bcast + 2;                   // [1] list-append cursor

    const float tx = tg[3*m+0], ty = tg[3*m+1], tz = tg[3*m+2];
    const float t2 = tx*tx + ty*ty + tz*tz;

    float* out_a = out;
    float* out_b = out + (size_t)MAX_ITERS * (size_t)M * 3;

    // gather fetch (plane point / list scan / solo fill): 3 dwords from pc.
    auto ldp = [&](int ip, float& x, float& y, float& z) {
        const float* p = pc + 3 * (size_t)ip;
        x = p[0]; y = p[1]; z = p[2];
    };

    // cross-wave finish: lexicographic (d2,idx) argmin + count sum; {idx,count}
    // returned to ALL threads via barrier-protected bcast (race-safe).
    auto finish = [&](float dmin, int imin, int mycnt, bool cntFromCursor) -> int2 {
        #pragma unroll
        for (int off = 32; off > 0; off >>= 1) {
            float od = __shfl_down(dmin, off, 64);
            int   oi = __shfl_down(imin, off, 64);
            int   oc = __shfl_down(mycnt, off, 64);
            if (od < dmin || (od == dmin && oi < imin)) { dmin = od; imin = oi; }
            mycnt += oc;
        }
        if (lane == 0) { red_d[wv] = dmin; red_i[wv] = imin; cw[wv] = mycnt; }
        __syncthreads();
        if (wv == 0) {
            float bd = (lane < NW) ? red_d[lane] : INFINITY;
            int   bi = (lane < NW) ? red_i[lane] : 0;
            int   c  = (lane < NW) ? cw[lane]    : 0;
            #pragma unroll
            for (int off = 8; off > 0; off >>= 1) {
                float od = __shfl_down(bd, off, 64);
                int   oi = __shfl_down(bi, off, 64);
                int   oc = __shfl_down(c,  off, 64);
                if (od < bd || (od == bd && oi < bi)) { bd = od; bi = oi; }
                c += oc;
            }
            if (lane == 0) { bcast[0] = bi; bcast[1] = cntFromCursor ? cnt[0] : c; }
        }
        __syncthreads();
        int2 r; r.x = bcast[0]; r.y = bcast[1];
        return r;
    };

    // Phase A: full-N scan, PT points/thread, slab-major (no rotation — R8:
    // lockstep streaming is constructive L2 sharing).
    // mode 0: all live, no plane test, no mask write (initial argmin)
    // mode 1: all live, test plane, write mask (k=0 cut; mask uninitialized)
    // mode 2: read mask, test plane, write mask
    auto scanA = [&](int mode, bool build,
                     float ax, float ay, float az, float b) -> int2 {
        if (tid == 0) cnt[0] = 0;
        __syncthreads();
        float dmin = INFINITY;
        int   imin = 0;
        int   mycnt = 0;
        for (int s = 0; s < stepsA; ++s) {
            const int ib    = s * PT * BLOCK + tid;
            const int wbase = s * (PT * BLOCK / 32);
            uint32_t live = 0;
            if (mode == 2) {
                #pragma unroll
                for (int j = 0; j < PT; ++j) {       // 8 independent broadcasts
                    uint32_t w = mask[wbase + j * (BLOCK / 32) + (tid >> 5)];
                    live |= ((w >> (tid & 31)) & 1u) << j;
                }
            } else {
                #pragma unroll
                for (int j = 0; j < PT; ++j)
                    if (ib + j * BLOCK < N) live |= (1u << j);
            }
            // UNCONDITIONAL clamped loads: all issued before any use (MLP=8).
            // Dead/tail lanes re-read point N-1; the live mask gates all uses.
            float px[PT], py[PT], pz[PT];
            #pragma unroll
            for (int j = 0; j < PT; ++j) {
                int ip = ib + j * BLOCK;
                ip = ip < N ? ip : N - 1;
                const float* p = pc + 3 * (size_t)ip;
                px[j] = p[0]; py[j] = p[1]; pz[j] = p[2];
            }
            uint32_t keepm = 0;
            #pragma unroll
            for (int j = 0; j < PT; ++j) {
                if ((live >> j) & 1u) {
                    bool keep;
                    if (mode == 0) keep = true;
                    else {
                        float dt = ax*px[j] + ay*py[j] + az*pz[j] - b;
                        keep = (dt < EPS_SEP);       // !(dt >= EPS_SEP)
                    }
                    if (keep) {
                        keepm |= (1u << j);
                        float p2 = px[j]*px[j] + py[j]*py[j] + pz[j]*pz[j];
                        float tp = tx*px[j] + ty*py[j] + tz*pz[j];
                        float d2 = t2 + p2 - 2.0f*tp;    // reference's exact form
                        const int i = ib + j * BLOCK;
                        if (d2 < dmin || (d2 == dmin && i < imin)) {
                            dmin = d2; imin = i;
                        }
                    }
                }
            }
            if (mode != 0) {
                #pragma unroll
                for (int j = 0; j < PT; ++j) {       // mask write: 2 lanes/wave/j
                    unsigned long long bal = __ballot(((keepm >> j) & 1u) != 0u);
                    const int widx = wbase + j * (BLOCK / 32) + (wv << 1);
                    if (lane == 0)       mask[widx]     = (uint32_t)bal;
                    else if (lane == 32) mask[widx + 1] = (uint32_t)(bal >> 32);
                }
            }
            mycnt += (int)__popc(keepm);
            if (build) {                             // compact survivors
                int c = (int)__popc(keepm);
                int incl = c;
                #pragma unroll
                for (int off = 1; off < 64; off <<= 1) {
                    int o = __shfl_up(incl, off, 64);
                    if (lane >= off) incl += o;
                }
                const int excl = incl - c;
                const int tot  = __shfl(incl, 63, 64);
                int wb = 0;
                if (lane == 0) wb = atomicAdd(cnt, tot);
                wb = __shfl(wb, 0, 64);
                int pos = wb + excl;
                #pragma unroll
                for (int j = 0; j < PT; ++j) {
                    if ((keepm >> j) & 1u) {
                        if (pos < CAP) list[pos] = ib + j * BLOCK;
                        ++pos;
                    }
                }
            }
        }
        return finish(dmin, imin, mycnt, false);
    };

    // Phase B: list scan, slab-major, in-place re-compaction. Safe: per
    // segment, all reads complete (barrier) before appends, and append
    // positions stay strictly below any unread segment.
    auto scanB = [&](int count, float ax, float ay, float az, float b) -> int2 {
        if (tid == 0) cnt[0] = 0;
        __syncthreads();
        float dmin = INFINITY;
        int   imin = 0;
        const int per = BLOCK * PB;
        const int bsteps = (count + per - 1) / per;
        for (int s = 0; s < bsteps; ++s) {
            int jv[PB]; float xv[PB], yv[PB], zv[PB];
            #pragma unroll
            for (int q = 0; q < PB; ++q) {           // unconditional clamped
                int e = s * per + q * BLOCK + tid;   // lane-stride 1
                e = e < count ? e : count - 1;
                jv[q] = list[e];
            }
            #pragma unroll
            for (int q = 0; q < PB; ++q)             // loads issued up front
                ldp(jv[q], xv[q], yv[q], zv[q]);
            uint32_t keepm = 0;
            float d2v[PB];
            #pragma unroll
            for (int q = 0; q < PB; ++q) {
                const int e = s * per + q * BLOCK + tid;
                if (e < count) {
                    float dt = ax*xv[q] + ay*yv[q] + az*zv[q] - b;
                    if (dt < EPS_SEP) {
                        keepm |= (1u << q);
                        float p2 = xv[q]*xv[q] + yv[q]*yv[q] + zv[q]*zv[q];
                        float tp = tx*xv[q] + ty*yv[q] + tz*zv[q];
                        d2v[q] = t2 + p2 - 2.0f*tp;
                    }
                }
            }
            __syncthreads();                         // reads done before appends
            int c = (int)__popc(keepm);
            int incl = c;
            #pragma unroll
            for (int off = 1; off < 64; off <<= 1) {
                int o = __shfl_up(incl, off, 64);
                if (lane >= off) incl += o;
            }
            const int excl = incl - c;
            const int tot  = __shfl(incl, 63, 64);
            int wb = 0;
            if (lane == 0) wb = atomicAdd(cnt, tot);
            wb = __shfl(wb, 0, 64);
            int pos = wb + excl;
            #pragma unroll
            for (int q = 0; q < PB; ++q) {
                if ((keepm >> q) & 1u) {
                    list[pos] = jv[q];
                    // list order arbitrary -> lexicographic for exact ties
                    if (d2v[q] < dmin || (d2v[q] == dmin && jv[q] < imin)) {
                        dmin = d2v[q]; imin = jv[q];
                    }
                    ++pos;
                }
            }
        }
        __syncthreads();                             // all appends/atomics done
        return finish(dmin, imin, 0, true);          // count from cursor
    };

    bool comp = false;
    int2 rc = scanA(0, false, 0.f, 0.f, 0.f, 0.f);
    int idx = rc.x, count = rc.y;                    // count = N here

    for (int k = 0; k < MAX_ITERS; ++k) {
        // Solo tail: wave 0 finishes barrier-free on LDS-resident coords.
        if (comp && count <= SOLO_CAP) {
            // Coord arrays in the dead upper list region:
            // SOLO_CAP + 3*SOLO_CAP <= CAP for CAP=32768 and CAP=8192.
            float* lx = (float*)(list + SOLO_CAP);
            float* ly = lx + SOLO_CAP;
            float* lz = ly + SOLO_CAP;
            for (int e = tid; e < count; e += BLOCK) {      // one gather
                float x, y, z;
                ldp(list[e], x, y, z);
                lx[e] = x; ly[e] = y; lz[e] = z;
            }
            __syncthreads();                         // fill done, uniform sync
            if (wv != 0) return;                     // LDS persists while any wave lives
            for (; k < MAX_ITERS; ++k) {
                float cx, cy, cz;
                ldp(idx, cx, cy, cz);
                const float vx = cx - tx, vy = cy - ty, vz = cz - tz;
                const float nrm = sqrtf(vx*vx + vy*vy + vz*vz);
                const float den = nrm + EPS_NORM;
                const float ax = vx / den, ay = vy / den, az = vz / den;
                const float b  = ax*cx + ay*cy + az*cz;
                if (count == 0) {                    // constant tail: bulk write
                    for (int q = lane; q < MAX_ITERS - k; q += 64) {
                        const int kk = k + q;
                        const size_t oa = ((size_t)kk * M + m) * 3;
                        out_a[oa+0] = ax; out_a[oa+1] = ay; out_a[oa+2] = az;
                        out_b[(size_t)kk * M + m] = b;
                    }
                    return;
                }
                if (lane == 0) {
                    const size_t oa = ((size_t)k * M + m) * 3;
                    out_a[oa+0] = ax; out_a[oa+1] = ay; out_a[oa+2] = az;
                    out_b[(size_t)k * M + m] = b;
                }
                if (k + 1 < MAX_ITERS) {
                    float dmin = INFINITY; int imin = 0; int wcur = 0;
                    for (int e0 = 0; e0 < count; e0 += 64) {
                        const int e = e0 + lane;
                        bool keep = false; int j = 0;
                        float d2v = 0.f, px = 0.f, py = 0.f, pz = 0.f;
                        if (e < count) {
                            j = list[e];
                            px = lx[e]; py = ly[e]; pz = lz[e];
                            float dt = ax*px + ay*py + az*pz - b;
                            if (dt < EPS_SEP) {
                                keep = true;
                                float p2 = px*px + py*py + pz*pz;
                                float tp = tx*px + ty*py + tz*pz;
                                d2v = t2 + p2 - 2.0f*tp;
                            }
                        }
                        // in-place compact: pos < wcur+64 <= e0+64; chunk
                        // [e0,e0+64) already in registers.
                        unsigned long long bal = __ballot(keep);
                        int pos = wcur + (int)__popcll(bal & ((1ull << lane) - 1ull));
                        if (keep) {
                            list[pos] = j;
                            lx[pos] = px; ly[pos] = py; lz[pos] = pz;
                            if (d2v < dmin || (d2v == dmin && j < imin)) {
                                dmin = d2v; imin = j;
                            }
                        }
                        wcur += (int)__popcll(bal);
                    }
                    #pragma unroll
                    for (int off = 32; off > 0; off >>= 1) {
                        float od = __shfl_down(dmin, off, 64);
                        int   oi = __shfl_down(imin, off, 64);
                        if (od < dmin || (od == dmin && oi < imin)) { dmin = od; imin = oi; }
                    }
                    idx = __shfl(imin, 0, 64);
                    count = wcur;                    // uniform across lanes
                }
            }
            return;
        }

        float cx, cy, cz;
        ldp(idx, cx, cy, cz);
        const float vx = cx - tx, vy = cy - ty, vz = cz - tz;
        const float nrm = sqrtf(vx*vx + vy*vy + vz*vz);
        const float den = nrm + EPS_NORM;
        const float ax = vx / den, ay = vy / den, az = vz / den;
        const float b  = ax*cx + ay*cy + az*cz;      // b = sum(a * closest)

        if (count == 0) {                            // constant tail: bulk write
            for (int q = tid; q < MAX_ITERS - k; q += BLOCK) {
                const int kk = k + q;
                const size_t oa = ((size_t)kk * M + m) * 3;
                out_a[oa+0] = ax; out_a[oa+1] = ay; out_a[oa+2] = az;
                out_b[(size_t)kk * M + m] = b;
            }
            return;
        }
        if (tid == 0) {
            const size_t oa = ((size_t)k * M + m) * 3;
            out_a[oa+0] = ax; out_a[oa+1] = ay; out_a[oa+2] = az;
            out_b[(size_t)k * M + m] = b;
        }
        if (k + 1 < MAX_ITERS) {                     // last update unobservable
            if (comp) {
                rc = scanB(count, ax, ay, az, b);
            } else {
                // attempt build early: failed build costs only a prefix scan
                const bool build = (count <= (5 * CAP) / 2);
                rc = scanA(k == 0 ? 1 : 2, build, ax, ay, az, b);
                if (build && rc.y <= CAP) comp = true;
            }
            idx = rc.x; count = rc.y;
        }
    }
}

extern "C" void kernel_launch(void* const* d_in, const int* in_sizes, int n_in,
                              void* d_out, int out_size, void* d_ws, size_t ws_size,
                              hipStream_t stream) {
    const float* pc = (const float*)d_in[0];
    const float* tg = (const float*)d_in[1];
    float* out = (float*)d_out;
    const int N = in_sizes[0] / 3;
    const int M = in_sizes[1] / 3;
    const int stepsA = (N + BLOCK * PT - 1) / (BLOCK * PT);
    const size_t maskB  = (size_t)stepsA * (PT * BLOCK / 32) * sizeof(uint32_t);
    const size_t fixedB = NW * (2 * sizeof(int) + sizeof(float)) + 3 * sizeof(int);

    int CAP = 32768;                                 // 128 KB list; total ~154 KB LDS
    size_t smem = maskB + (size_t)CAP * sizeof(int) + fixedB;
    if (hipFuncSetAttribute((const void*)convex_plane_kernel,
                            hipFuncAttributeMaxDynamicSharedMemorySize,
                            (int)smem) != hipSuccess) {
        CAP = 8192;                                  // stay within default 64 KB
        smem = maskB + (size_t)CAP * sizeof(int) + fixedB;
    }
    convex_plane_kernel<<<M, BLOCK, smem, stream>>>(pc, tg, out, N, M, CAP, stepsA);
}